// Round 9
// baseline (1558.432 us; speedup 1.0000x reference)
//
#include <hip/hip_runtime.h>
#include <hip/hip_bf16.h>
#include <math.h>

// ---------------- problem constants ----------------
constexpr int N_NODES  = 20000;
constexpr int M_PAD    = 20096;   // 157 * 128 row tiles
constexpr int E_EDGES  = 320000;
constexpr int G_GRAPHS = 64;
constexpr int F_IN     = 128;
constexpr int H_DIM    = 256;
constexpr int LAYERS   = 8;
constexpr float SCALE_ATT = 0.17677669529663687f; // 1/sqrt(32)

typedef __attribute__((ext_vector_type(8))) short bf16x8;
typedef __attribute__((ext_vector_type(4))) float f32x4;
typedef _Float16 half4 __attribute__((ext_vector_type(4)));
typedef unsigned int u32;

// ---------------- CSR build ----------------
__global__ void count_kernel(const int* __restrict__ dst, int E, int* __restrict__ counts) {
    int i = blockIdx.x * blockDim.x + threadIdx.x;
    if (i < E) atomicAdd(&counts[dst[i]], 1);
}

// wave-shfl based scan: 1024 threads = 16 waves
__global__ __launch_bounds__(1024) void scan_kernel(const int* __restrict__ counts,
                                                    int* __restrict__ offsets, int n) {
    __shared__ int wsum[16];
    __shared__ int carry_s;
    const int t = threadIdx.x;
    const int lane = t & 63, w = t >> 6;
    if (t == 0) { carry_s = 0; offsets[0] = 0; }
    __syncthreads();
    for (int base = 0; base < n; base += 1024) {
        const int i = base + t;
        const int v = (i < n) ? counts[i] : 0;
        int s = v;
        #pragma unroll
        for (int off = 1; off < 64; off <<= 1) {
            int x = __shfl_up(s, off, 64);
            if (lane >= off) s += x;
        }
        if (lane == 63) wsum[w] = s;
        __syncthreads();
        if (w == 0) {
            int x = (lane < 16) ? wsum[lane] : 0;
            #pragma unroll
            for (int off = 1; off < 16; off <<= 1) {
                int y = __shfl_up(x, off, 64);
                if (lane >= off) x += y;
            }
            if (lane < 16) wsum[lane] = x;
        }
        __syncthreads();
        const int wadd = (w > 0) ? wsum[w - 1] : 0;
        const int inc = carry_s + wadd + s;
        if (i < n) offsets[i + 1] = inc;
        __syncthreads();
        if (t == 1023) carry_s = inc;
        __syncthreads();
    }
}

__global__ void scatter_kernel(const int* __restrict__ src, const int* __restrict__ dst, int E,
                               const int* __restrict__ offsets, int* __restrict__ cursor,
                               int* __restrict__ esrc) {
    int i = blockIdx.x * blockDim.x + threadIdx.x;
    if (i < E) {
        int d = dst[i];
        int pos = atomicAdd(&cursor[d], 1);
        esrc[offsets[d] + pos] = src[i];
    }
}

// ---------------- weight transpose + hi/lo bf16 split ----------------
__global__ __launch_bounds__(256) void wt_layers(
        const float* __restrict__ Wq, const float* __restrict__ Wk,
        const float* __restrict__ Wv, const float* __restrict__ Ws,
        __hip_bfloat16* __restrict__ Whi, __hip_bfloat16* __restrict__ Wlo) {
    const int l = blockIdx.z, z = blockIdx.y;
    const int tk = (blockIdx.x & 7) * 32;
    const int tn = (blockIdx.x >> 3) * 32;
    const float* src = (z == 0 ? Wq : z == 1 ? Wk : z == 2 ? Wv : Ws) + (size_t)l * 65536;
    __shared__ float tile[32][33];
    const int tx = threadIdx.x & 31, ty = threadIdx.x >> 5;
    #pragma unroll
    for (int p = 0; p < 4; ++p)
        tile[ty + p * 8][tx] = src[(size_t)(tk + ty + p * 8) * 256 + tn + tx];
    __syncthreads();
    #pragma unroll
    for (int p = 0; p < 4; ++p) {
        int n = tn + ty + p * 8;
        float v = tile[tx][ty + p * 8];
        size_t o = ((size_t)l * 1024 + z * 256 + n) * 256 + tk + tx;
        __hip_bfloat16 hi = __float2bfloat16(v);
        Whi[o] = hi;
        Wlo[o] = __float2bfloat16(v - __bfloat162float(hi));
    }
}

__global__ __launch_bounds__(256) void wt_init(const float* __restrict__ Wi,
        __hip_bfloat16* __restrict__ Whi, __hip_bfloat16* __restrict__ Wlo) {
    const int tk = (blockIdx.x & 3) * 32;
    const int tn = (blockIdx.x >> 2) * 32;
    __shared__ float tile[32][33];
    const int tx = threadIdx.x & 31, ty = threadIdx.x >> 5;
    #pragma unroll
    for (int p = 0; p < 4; ++p)
        tile[ty + p * 8][tx] = Wi[(size_t)(tk + ty + p * 8) * 256 + tn + tx];
    __syncthreads();
    #pragma unroll
    for (int p = 0; p < 4; ++p) {
        int n = tn + ty + p * 8;
        float v = tile[tx][ty + p * 8];
        size_t o = (size_t)n * 128 + tk + tx;
        __hip_bfloat16 hi = __float2bfloat16(v);
        Whi[o] = hi;
        Wlo[o] = __float2bfloat16(v - __bfloat162float(hi));
    }
}

__global__ __launch_bounds__(256) void bias_cat(const float* __restrict__ bq,
        const float* __restrict__ bk, const float* __restrict__ bv,
        const float* __restrict__ bs, float* __restrict__ bcat) {
    int l = blockIdx.x >> 2, z = blockIdx.x & 3;
    const float* b = (z == 0 ? bq : z == 1 ? bk : z == 2 ? bv : bs) + (size_t)l * 256;
    bcat[(size_t)l * 1024 + z * 256 + threadIdx.x] = b[threadIdx.x];
}

__global__ void conv_hi_lo(const float* __restrict__ src, int n,
                           __hip_bfloat16* __restrict__ hi, __hip_bfloat16* __restrict__ lo) {
    int i = blockIdx.x * blockDim.x + threadIdx.x;
    if (i < n) {
        float v = src[i];
        __hip_bfloat16 h = __float2bfloat16(v);
        hi[i] = h;
        lo[i] = __float2bfloat16(v - __bfloat162float(h));
    }
}

// ---------------- split-precision bf16 MFMA GEMM — DIRECT (no LDS, no barriers) ----
// A/B fragments for mfma_16x16x32 are 16B contiguous-in-K per lane -> plain
// bf16x8 global loads; waves pipeline independently.
// WRITE_MODE 0: qs (fp32 q*SCALE | s) + kv (fp16 k|v). WRITE_MODE 1: bf16 hi/lo.
template <int WRITE_MODE>
__global__ __launch_bounds__(256) void gemm_mfma(
        const __hip_bfloat16* __restrict__ Ahi, const __hip_bfloat16* __restrict__ Alo,
        const __hip_bfloat16* __restrict__ Bhi, const __hip_bfloat16* __restrict__ Blo,
        const float* __restrict__ bias, int M, int K,
        float* __restrict__ qs, _Float16* __restrict__ kv,
        __hip_bfloat16* __restrict__ Chi, __hip_bfloat16* __restrict__ Clo) {
    const int t = threadIdx.x;
    const int lane = t & 63, wave = t >> 6;

    // bijective XCD chunk swizzle (m204)
    const int nwg = gridDim.x * gridDim.y;
    const int lid = blockIdx.y * gridDim.x + blockIdx.x;
    const int qch = nwg >> 3, rch = nwg & 7;
    const int xcd = lid & 7, pos = lid >> 3;
    const int swz = (xcd < rch ? xcd * (qch + 1) : rch * (qch + 1) + (xcd - rch) * qch) + pos;
    const int row0 = (swz / gridDim.x) * 128;
    const int col0 = (swz % gridDim.x) * 128;

    const int wr = wave >> 1, wc = wave & 1;
    const int rA = row0 + wr * 64 + (lane & 15);
    const int rB = col0 + wc * 64 + (lane & 15);
    const int kq = (lane >> 4) * 8;

    const __hip_bfloat16* pAhi = Ahi + (size_t)rA * K + kq;
    const __hip_bfloat16* pAlo = Alo + (size_t)rA * K + kq;
    const __hip_bfloat16* pBhi = Bhi + (size_t)rB * K + kq;
    const __hip_bfloat16* pBlo = Blo + (size_t)rB * K + kq;
    const size_t fstride = (size_t)16 * K;   // fragment row-block stride (elements)

    f32x4 acc[4][4] = {};

    const int nK = K >> 5;
    #pragma unroll 2
    for (int ks = 0; ks < nK; ++ks) {
        const int ko = ks * 32;
        bf16x8 ah[4], al[4], bh[4], bl[4];
        #pragma unroll
        for (int f = 0; f < 4; ++f) {
            ah[f] = *(const bf16x8*)(pAhi + f * fstride + ko);
            al[f] = *(const bf16x8*)(pAlo + f * fstride + ko);
            bh[f] = *(const bf16x8*)(pBhi + f * fstride + ko);
            bl[f] = *(const bf16x8*)(pBlo + f * fstride + ko);
        }
        #pragma unroll
        for (int i = 0; i < 4; ++i)
            #pragma unroll
            for (int j = 0; j < 4; ++j) {
                acc[i][j] = __builtin_amdgcn_mfma_f32_16x16x32_bf16(al[i], bh[j], acc[i][j], 0, 0, 0);
                acc[i][j] = __builtin_amdgcn_mfma_f32_16x16x32_bf16(ah[i], bl[j], acc[i][j], 0, 0, 0);
                acc[i][j] = __builtin_amdgcn_mfma_f32_16x16x32_bf16(ah[i], bh[j], acc[i][j], 0, 0, 0);
            }
    }

    // epilogue: C/D frag layout col=lane&15, row=(lane>>4)*4+reg  [m89-verified]
    const int rb = row0 + wr * 64;
    const int cb = col0 + wc * 64;
    #pragma unroll
    for (int i = 0; i < 4; ++i) {
        #pragma unroll
        for (int j = 0; j < 4; ++j) {
            const int c = cb + j * 16 + (lane & 15);
            const float bz = bias[c];
            #pragma unroll
            for (int rg = 0; rg < 4; ++rg) {
                const int r = rb + i * 16 + (lane >> 4) * 4 + rg;
                if (r < M) {
                    const float v = acc[i][j][rg] + bz;
                    if (WRITE_MODE == 0) {
                        const int sec = c >> 8;   // 0=q 1=k 2=v 3=s (uniform per tile)
                        if (sec == 0)      qs[(size_t)r * 512 + c] = v * SCALE_ATT;
                        else if (sec == 3) qs[(size_t)r * 512 + c - 512] = v;
                        else               kv[(size_t)r * 512 + c - 256] = (_Float16)v;
                    } else {
                        __hip_bfloat16 hi = __float2bfloat16(v);
                        Chi[(size_t)r * 256 + c] = hi;
                        Clo[(size_t)r * 256 + c] = __float2bfloat16(v - __bfloat162float(hi));
                    }
                }
            }
        }
    }
}

// ---------------- fused attention: block=node, wave-per-edge, 4-deep pipeline ----
// No-max softmax: alpha = q.k*scale is analytically bounded (|a| < ~10) for this
// model, so exp(alpha) is fp32-safe and softmax is mathematically identical.
// WH==0: write h_hi/h_lo only. WH==1: last layer, write h fp32 only.
template <int WH>
__global__ __launch_bounds__(256) void node_attn_kernel(
        const float* __restrict__ qs, const _Float16* __restrict__ kv,
        const int* __restrict__ offsets,
        const int* __restrict__ esrc, const float* __restrict__ Wbeta,
        const float* __restrict__ ln_g, const float* __restrict__ ln_b,
        float* __restrict__ h_out,
        __hip_bfloat16* __restrict__ h_hi, __hip_bfloat16* __restrict__ h_lo) {
    const int n = blockIdx.x;
    const int t = threadIdx.x;
    const int lane = t & 63, wave = t >> 6;
    __shared__ int s_src[256];
    __shared__ float s_acc[4][256];
    __shared__ float s_s[4][8];
    __shared__ float red[8];
    __shared__ float s_beta;

    const float4 q4 = reinterpret_cast<const float4*>(qs + (size_t)n * 512)[lane];

    float ssum = 0.f;
    float4 accv = make_float4(0.f, 0.f, 0.f, 0.f);
    const int rs = offsets[n], re = offsets[n + 1];

#define LOADKV(KB, VB, J) { const half4* r_ = reinterpret_cast<const half4*>(kv + (size_t)s_src[(J)] * 512); \
                            KB = r_[lane]; VB = r_[64 + lane]; }
#define STEP(KB, VB) { \
    float p_ = q4.x * (float)KB.x + q4.y * (float)KB.y + q4.z * (float)KB.z + q4.w * (float)KB.w; \
    p_ += __shfl_xor(p_, 1, 8); p_ += __shfl_xor(p_, 2, 8); p_ += __shfl_xor(p_, 4, 8); \
    const float e_ = __expf(p_); \
    ssum += e_; \
    accv.x += e_ * (float)VB.x; \
    accv.y += e_ * (float)VB.y; \
    accv.z += e_ * (float)VB.z; \
    accv.w += e_ * (float)VB.w; }

    for (int base = rs; base < re; base += 256) {
        const int cnt = min(re - base, 256);
        if (t < cnt) s_src[t] = esrc[base + t];
        __syncthreads();

        half4 k0, v0, k1, v1, k2, v2, k3, v3;
        int j = wave;
        if (j      < cnt) LOADKV(k0, v0, j);
        if (j + 4  < cnt) LOADKV(k1, v1, j + 4);
        if (j + 8  < cnt) LOADKV(k2, v2, j + 8);
        if (j + 12 < cnt) LOADKV(k3, v3, j + 12);

        while (j < cnt) {
            STEP(k0, v0); if (j + 16 < cnt) LOADKV(k0, v0, j + 16); j += 4;
            if (j >= cnt) break;
            STEP(k1, v1); if (j + 16 < cnt) LOADKV(k1, v1, j + 16); j += 4;
            if (j >= cnt) break;
            STEP(k2, v2); if (j + 16 < cnt) LOADKV(k2, v2, j + 16); j += 4;
            if (j >= cnt) break;
            STEP(k3, v3); if (j + 16 < cnt) LOADKV(k3, v3, j + 16); j += 4;
        }
        __syncthreads();
    }
#undef LOADKV
#undef STEP

    // merge 4 per-wave partials (plain sums — no max tracking)
    *reinterpret_cast<float4*>(&s_acc[wave][lane * 4]) = accv;
    if ((lane & 7) == 0) s_s[wave][lane >> 3] = ssum;
    __syncthreads();

    const int hd = t >> 5;
    const float den = s_s[0][hd] + s_s[1][hd] + s_s[2][hd] + s_s[3][hd];
    const float out = (s_acc[0][t] + s_acc[1][t] + s_acc[2][t] + s_acc[3][t]) / (den + 1e-16f);

    const float xr = qs[(size_t)n * 512 + 256 + t];

    float bl = out * (Wbeta[t] + Wbeta[512 + t]) + xr * (Wbeta[256 + t] - Wbeta[512 + t]);
    #pragma unroll
    for (int o = 32; o >= 1; o >>= 1) bl += __shfl_xor(bl, o, 64);
    if ((t & 63) == 0) red[wave] = bl;
    __syncthreads();
    if (t == 0) {
        float v = red[0] + red[1] + red[2] + red[3];
        s_beta = 1.f / (1.f + __expf(-v));
    }
    __syncthreads();
    const float beta = s_beta;
    const float hn = beta * xr + (1.f - beta) * out;

    float r1 = hn;
    #pragma unroll
    for (int o = 32; o >= 1; o >>= 1) r1 += __shfl_xor(r1, o, 64);
    if ((t & 63) == 0) red[4 + wave] = r1;
    __syncthreads();
    const float mu = (red[4] + red[5] + red[6] + red[7]) * (1.f / 256.f);
    const float d = hn - mu;
    float r2 = d * d;
    #pragma unroll
    for (int o = 32; o >= 1; o >>= 1) r2 += __shfl_xor(r2, o, 64);
    if ((t & 63) == 0) red[wave] = r2;
    __syncthreads();
    const float var = (red[0] + red[1] + red[2] + red[3]) * (1.f / 256.f);

    float y = d * rsqrtf(var + 1e-5f) * ln_g[t] + ln_b[t];
    y = fmaxf(y, 0.f);
    if (WH == 1) {
        h_out[(size_t)n * 256 + t] = y;
    } else {
        __hip_bfloat16 hi = __float2bfloat16(y);
        h_hi[(size_t)n * 256 + t] = hi;
        h_lo[(size_t)n * 256 + t] = __float2bfloat16(y - __bfloat162float(hi));
    }
}

// ---------------- mean pool (batch sorted): 32 nodes/block, register-staged ----
constexpr int POOL_N = 32;
__global__ __launch_bounds__(256) void pool_kernel(const float* __restrict__ h,
                                                   const int* __restrict__ batch, int Nn,
                                                   float* __restrict__ sums,
                                                   float* __restrict__ cnt) {
    const int start = blockIdx.x * POOL_N;
    const int end = min(start + POOL_N, Nn);
    if (start >= end) return;
    const int t = threadIdx.x;

    float val[POOL_N];
    #pragma unroll
    for (int i = 0; i < POOL_N; ++i) {
        const int n = start + i;
        val[i] = (n < end) ? h[(size_t)n * 256 + t] : 0.f;
    }

    int cur = batch[start];
    float run = 0.f;
    int c = 0;
    #pragma unroll
    for (int i = 0; i < POOL_N; ++i) {
        const int n = start + i;
        if (n >= end) break;
        const int g = batch[n];
        if (g != cur) {
            atomicAdd(&sums[(size_t)cur * 256 + t], run);
            if (t == 0) atomicAdd(&cnt[cur], (float)c);
            run = 0.f; c = 0; cur = g;
        }
        run += val[i];
        ++c;
    }
    atomicAdd(&sums[(size_t)cur * 256 + t], run);
    if (t == 0) atomicAdd(&cnt[cur], (float)c);
}

__global__ __launch_bounds__(128) void final_kernel(const float* __restrict__ sums,
                                                    const float* __restrict__ cnt,
                                                    const float* __restrict__ Wf,
                                                    const float* __restrict__ bf,
                                                    float* __restrict__ out) {
    const int g = blockIdx.x;
    const int t = threadIdx.x;
    __shared__ float p[256];
    const float c = fmaxf(cnt[g], 1.f);
    for (int i = t; i < 256; i += 128) p[i] = sums[(size_t)g * 256 + i] / c;
    __syncthreads();
    float acc = bf[t];
    #pragma unroll 4
    for (int k = 0; k < 256; ++k) acc += p[k] * Wf[k * 128 + t];
    out[(size_t)g * 128 + t] = acc;
}

// ---------------- launcher ----------------
extern "C" void kernel_launch(void* const* d_in, const int* in_sizes, int n_in,
                              void* d_out, int out_size, void* d_ws, size_t ws_size,
                              hipStream_t stream) {
    const float* x       = (const float*)d_in[0];
    const int*   eidx    = (const int*)  d_in[1];
    const int*   batch   = (const int*)  d_in[2];
    const float* W_init  = (const float*)d_in[3];
    const float* b_init  = (const float*)d_in[4];
    const float* Wq      = (const float*)d_in[5];
    const float* bq      = (const float*)d_in[6];
    const float* Wk      = (const float*)d_in[7];
    const float* bk      = (const float*)d_in[8];
    const float* Wv      = (const float*)d_in[9];
    const float* bv      = (const float*)d_in[10];
    const float* Ws      = (const float*)d_in[11];
    const float* bs      = (const float*)d_in[12];
    const float* Wbeta   = (const float*)d_in[13];
    const float* ln_g    = (const float*)d_in[14];
    const float* ln_b    = (const float*)d_in[15];
    const float* W_final = (const float*)d_in[16];
    const float* b_final = (const float*)d_in[17];

    const int* e_src = eidx;
    const int* e_dst = eidx + E_EDGES;

    char* p = (char*)d_ws;
    auto alloc = [&](size_t bytes) {
        void* r = (void*)p;
        p += (bytes + 255) & ~(size_t)255;
        return r;
    };
    float* h      = (float*)alloc((size_t)M_PAD * 256 * 4);
    float* qs     = (float*)alloc((size_t)N_NODES * 512 * 4);
    _Float16* kv  = (_Float16*)alloc((size_t)N_NODES * 512 * 2);
    __hip_bfloat16* h_hi = (__hip_bfloat16*)alloc((size_t)M_PAD * 256 * 2);
    __hip_bfloat16* h_lo = (__hip_bfloat16*)alloc((size_t)M_PAD * 256 * 2);
    __hip_bfloat16* x_hi = (__hip_bfloat16*)alloc((size_t)M_PAD * 128 * 2);
    __hip_bfloat16* x_lo = (__hip_bfloat16*)alloc((size_t)M_PAD * 128 * 2);
    __hip_bfloat16* Wt_hi = (__hip_bfloat16*)alloc((size_t)LAYERS * 1024 * 256 * 2);
    __hip_bfloat16* Wt_lo = (__hip_bfloat16*)alloc((size_t)LAYERS * 1024 * 256 * 2);
    __hip_bfloat16* Wi_hi = (__hip_bfloat16*)alloc((size_t)256 * 128 * 2);
    __hip_bfloat16* Wi_lo = (__hip_bfloat16*)alloc((size_t)256 * 128 * 2);
    float* bcat   = (float*)alloc((size_t)LAYERS * 1024 * 4);
    int* counts   = (int*)alloc((size_t)N_NODES * 4);
    int* offsets  = (int*)alloc((size_t)(N_NODES + 1) * 4);
    int* cursor   = (int*)alloc((size_t)N_NODES * 4);
    int* esrc     = (int*)alloc((size_t)E_EDGES * 4);
    float* sums   = (float*)alloc((size_t)G_GRAPHS * 256 * 4);
    float* cnt    = (float*)alloc((size_t)G_GRAPHS * 4);

    hipMemsetAsync(counts, 0, sizeof(int) * N_NODES, stream);
    hipMemsetAsync(cursor, 0, sizeof(int) * N_NODES, stream);
    hipMemsetAsync(sums, 0, sizeof(float) * G_GRAPHS * 256, stream);
    hipMemsetAsync(cnt, 0, sizeof(float) * G_GRAPHS, stream);

    count_kernel<<<(E_EDGES + 255) / 256, 256, 0, stream>>>(e_dst, E_EDGES, counts);
    scan_kernel<<<1, 1024, 0, stream>>>(counts, offsets, N_NODES);
    scatter_kernel<<<(E_EDGES + 255) / 256, 256, 0, stream>>>(e_src, e_dst, E_EDGES,
                                                              offsets, cursor, esrc);

    wt_layers<<<dim3(64, 4, LAYERS), 256, 0, stream>>>(Wq, Wk, Wv, Ws, Wt_hi, Wt_lo);
    wt_init<<<32, 256, 0, stream>>>(W_init, Wi_hi, Wi_lo);
    bias_cat<<<LAYERS * 4, 256, 0, stream>>>(bq, bk, bv, bs, bcat);
    conv_hi_lo<<<(N_NODES * 128 + 255) / 256, 256, 0, stream>>>(x, N_NODES * 128, x_hi, x_lo);

    const int rowTiles = M_PAD / 128;   // 157

    gemm_mfma<1><<<dim3(2, rowTiles), 256, 0, stream>>>(
        x_hi, x_lo, Wi_hi, Wi_lo, b_init, N_NODES, 128,
        nullptr, nullptr, h_hi, h_lo);

    for (int l = 0; l < LAYERS; ++l) {
        gemm_mfma<0><<<dim3(8, rowTiles), 256, 0, stream>>>(
            h_hi, h_lo,
            Wt_hi + (size_t)l * 1024 * 256, Wt_lo + (size_t)l * 1024 * 256,
            bcat + (size_t)l * 1024, N_NODES, 256,
            qs, kv, nullptr, nullptr);

        if (l < LAYERS - 1) {
            node_attn_kernel<0><<<N_NODES, 256, 0, stream>>>(
                qs, kv, offsets, esrc,
                Wbeta + (size_t)l * 768,
                ln_g + (size_t)l * 256, ln_b + (size_t)l * 256,
                nullptr, h_hi, h_lo);
        } else {
            node_attn_kernel<1><<<N_NODES, 256, 0, stream>>>(
                qs, kv, offsets, esrc,
                Wbeta + (size_t)l * 768,
                ln_g + (size_t)l * 256, ln_b + (size_t)l * 256,
                h, nullptr, nullptr);
        }
    }

    pool_kernel<<<(N_NODES + POOL_N - 1) / POOL_N, 256, 0, stream>>>(h, batch, N_NODES, sums, cnt);
    final_kernel<<<G_GRAPHS, 128, 0, stream>>>(sums, cnt, W_final, b_final, (float*)d_out);
}

// Round 10
// 1122.868 us; speedup vs baseline: 1.3879x; 1.3879x over previous
//
#include <hip/hip_runtime.h>
#include <hip/hip_bf16.h>
#include <math.h>

// ---------------- problem constants ----------------
constexpr int N_NODES  = 20000;
constexpr int M_PAD    = 20096;   // 157 * 128 row tiles
constexpr int E_EDGES  = 320000;
constexpr int G_GRAPHS = 64;
constexpr int F_IN     = 128;
constexpr int H_DIM    = 256;
constexpr int LAYERS   = 8;
constexpr float SCALE_ATT = 0.17677669529663687f; // 1/sqrt(32)

typedef __attribute__((ext_vector_type(8))) short bf16x8;
typedef __attribute__((ext_vector_type(4))) float f32x4;
typedef _Float16 half4 __attribute__((ext_vector_type(4)));
typedef unsigned int u32;

__device__ static inline void gload_lds16(void* lds, const void* g) {
    __builtin_amdgcn_global_load_lds((const __attribute__((address_space(1))) u32*)g,
                                     (__attribute__((address_space(3))) u32*)lds, 16, 0, 0);
}

// ---------------- CSR build ----------------
__global__ void count_kernel(const int* __restrict__ dst, int E, int* __restrict__ counts) {
    int i = blockIdx.x * blockDim.x + threadIdx.x;
    if (i < E) atomicAdd(&counts[dst[i]], 1);
}

// wave-shfl based scan: 1024 threads = 16 waves
__global__ __launch_bounds__(1024) void scan_kernel(const int* __restrict__ counts,
                                                    int* __restrict__ offsets, int n) {
    __shared__ int wsum[16];
    __shared__ int carry_s;
    const int t = threadIdx.x;
    const int lane = t & 63, w = t >> 6;
    if (t == 0) { carry_s = 0; offsets[0] = 0; }
    __syncthreads();
    for (int base = 0; base < n; base += 1024) {
        const int i = base + t;
        const int v = (i < n) ? counts[i] : 0;
        int s = v;
        #pragma unroll
        for (int off = 1; off < 64; off <<= 1) {
            int x = __shfl_up(s, off, 64);
            if (lane >= off) s += x;
        }
        if (lane == 63) wsum[w] = s;
        __syncthreads();
        if (w == 0) {
            int x = (lane < 16) ? wsum[lane] : 0;
            #pragma unroll
            for (int off = 1; off < 16; off <<= 1) {
                int y = __shfl_up(x, off, 64);
                if (lane >= off) x += y;
            }
            if (lane < 16) wsum[lane] = x;
        }
        __syncthreads();
        const int wadd = (w > 0) ? wsum[w - 1] : 0;
        const int inc = carry_s + wadd + s;
        if (i < n) offsets[i + 1] = inc;
        __syncthreads();
        if (t == 1023) carry_s = inc;
        __syncthreads();
    }
}

__global__ void scatter_kernel(const int* __restrict__ src, const int* __restrict__ dst, int E,
                               const int* __restrict__ offsets, int* __restrict__ cursor,
                               int* __restrict__ esrc) {
    int i = blockIdx.x * blockDim.x + threadIdx.x;
    if (i < E) {
        int d = dst[i];
        int pos = atomicAdd(&cursor[d], 1);
        esrc[offsets[d] + pos] = src[i];
    }
}

// ---------------- weight transpose + hi/lo bf16 split ----------------
__global__ __launch_bounds__(256) void wt_layers(
        const float* __restrict__ Wq, const float* __restrict__ Wk,
        const float* __restrict__ Wv, const float* __restrict__ Ws,
        __hip_bfloat16* __restrict__ Whi, __hip_bfloat16* __restrict__ Wlo) {
    const int l = blockIdx.z, z = blockIdx.y;
    const int tk = (blockIdx.x & 7) * 32;
    const int tn = (blockIdx.x >> 3) * 32;
    const float* src = (z == 0 ? Wq : z == 1 ? Wk : z == 2 ? Wv : Ws) + (size_t)l * 65536;
    __shared__ float tile[32][33];
    const int tx = threadIdx.x & 31, ty = threadIdx.x >> 5;
    #pragma unroll
    for (int p = 0; p < 4; ++p)
        tile[ty + p * 8][tx] = src[(size_t)(tk + ty + p * 8) * 256 + tn + tx];
    __syncthreads();
    #pragma unroll
    for (int p = 0; p < 4; ++p) {
        int n = tn + ty + p * 8;
        float v = tile[tx][ty + p * 8];
        size_t o = ((size_t)l * 1024 + z * 256 + n) * 256 + tk + tx;
        __hip_bfloat16 hi = __float2bfloat16(v);
        Whi[o] = hi;
        Wlo[o] = __float2bfloat16(v - __bfloat162float(hi));
    }
}

__global__ __launch_bounds__(256) void wt_init(const float* __restrict__ Wi,
        __hip_bfloat16* __restrict__ Whi, __hip_bfloat16* __restrict__ Wlo) {
    const int tk = (blockIdx.x & 3) * 32;
    const int tn = (blockIdx.x >> 2) * 32;
    __shared__ float tile[32][33];
    const int tx = threadIdx.x & 31, ty = threadIdx.x >> 5;
    #pragma unroll
    for (int p = 0; p < 4; ++p)
        tile[ty + p * 8][tx] = Wi[(size_t)(tk + ty + p * 8) * 256 + tn + tx];
    __syncthreads();
    #pragma unroll
    for (int p = 0; p < 4; ++p) {
        int n = tn + ty + p * 8;
        float v = tile[tx][ty + p * 8];
        size_t o = (size_t)n * 128 + tk + tx;
        __hip_bfloat16 hi = __float2bfloat16(v);
        Whi[o] = hi;
        Wlo[o] = __float2bfloat16(v - __bfloat162float(hi));
    }
}

__global__ __launch_bounds__(256) void bias_cat(const float* __restrict__ bq,
        const float* __restrict__ bk, const float* __restrict__ bv,
        const float* __restrict__ bs, float* __restrict__ bcat) {
    int l = blockIdx.x >> 2, z = blockIdx.x & 3;
    const float* b = (z == 0 ? bq : z == 1 ? bk : z == 2 ? bv : bs) + (size_t)l * 256;
    bcat[(size_t)l * 1024 + z * 256 + threadIdx.x] = b[threadIdx.x];
}

__global__ void conv_hi_lo(const float* __restrict__ src, int n,
                           __hip_bfloat16* __restrict__ hi, __hip_bfloat16* __restrict__ lo) {
    int i = blockIdx.x * blockDim.x + threadIdx.x;
    if (i < n) {
        float v = src[i];
        __hip_bfloat16 h = __float2bfloat16(v);
        hi[i] = h;
        lo[i] = __float2bfloat16(v - __bfloat162float(h));
    }
}

// ---------------- split-precision bf16 MFMA GEMM (LDS-staged, 2-phase prefetch) ----
// Double-buffered LDS: stage tile ks+1 BEFORE computing tile ks; one barrier
// per K-step (prefetch latency hides under ds_read + 48 MFMAs).
// WRITE_MODE 0: qs (fp32 q*SCALE | s) + kv (fp16 k|v). WRITE_MODE 1: bf16 hi/lo.
template <int WRITE_MODE>
__global__ __launch_bounds__(256) void gemm_mfma(
        const __hip_bfloat16* __restrict__ Ahi, const __hip_bfloat16* __restrict__ Alo,
        const __hip_bfloat16* __restrict__ Bhi, const __hip_bfloat16* __restrict__ Blo,
        const float* __restrict__ bias, int M, int K,
        float* __restrict__ qs, _Float16* __restrict__ kv,
        __hip_bfloat16* __restrict__ Chi, __hip_bfloat16* __restrict__ Clo) {
    const int t = threadIdx.x;
    const int lane = t & 63, wave = t >> 6;

    // bijective XCD chunk swizzle (m204)
    const int nwg = gridDim.x * gridDim.y;
    const int lid = blockIdx.y * gridDim.x + blockIdx.x;
    const int qch = nwg >> 3, rch = nwg & 7;
    const int xcd = lid & 7, pos = lid >> 3;
    const int swz = (xcd < rch ? xcd * (qch + 1) : rch * (qch + 1) + (xcd - rch) * qch) + pos;
    const int row0 = (swz / gridDim.x) * 128;
    const int col0 = (swz % gridDim.x) * 128;

    __shared__ __align__(16) __hip_bfloat16 smem[2][4][4096];   // 64 KB

    const int ch0 = wave * 64 + lane;
    const int ch1 = ch0 + 256;
    const int rA0 = ch0 >> 2, cA0 = (ch0 & 3) ^ ((rA0 >> 1) & 3);
    const int rA1 = ch1 >> 2, cA1 = (ch1 & 3) ^ ((rA1 >> 1) & 3);
    const size_t gOff0 = (size_t)rA0 * K + cA0 * 8;
    const size_t gOff1 = (size_t)rA1 * K + cA1 * 8;
    const size_t gA0 = (size_t)row0 * K + gOff0, gA1 = (size_t)row0 * K + gOff1;
    const size_t gB0 = (size_t)col0 * K + gOff0, gB1 = (size_t)col0 * K + gOff1;

    const int wr = wave >> 1, wc = wave & 1;
    int offA[4], offB[4];
    #pragma unroll
    for (int f = 0; f < 4; ++f) {
        int ra = wr * 64 + f * 16 + (lane & 15);
        offA[f] = ra * 64 + (((lane >> 4) ^ ((ra >> 1) & 3)) << 4);
        int rb = wc * 64 + f * 16 + (lane & 15);
        offB[f] = rb * 64 + (((lane >> 4) ^ ((rb >> 1) & 3)) << 4);
    }

    f32x4 acc[4][4] = {};
    const int nK = K >> 5;

#define STAGE(BUF, KS) { const size_t ko_ = (size_t)(KS) * 32; \
    gload_lds16((char*)&smem[BUF][0][0] + ch0 * 16, Ahi + gA0 + ko_); \
    gload_lds16((char*)&smem[BUF][0][0] + ch1 * 16, Ahi + gA1 + ko_); \
    gload_lds16((char*)&smem[BUF][1][0] + ch0 * 16, Alo + gA0 + ko_); \
    gload_lds16((char*)&smem[BUF][1][0] + ch1 * 16, Alo + gA1 + ko_); \
    gload_lds16((char*)&smem[BUF][2][0] + ch0 * 16, Bhi + gB0 + ko_); \
    gload_lds16((char*)&smem[BUF][2][0] + ch1 * 16, Bhi + gB1 + ko_); \
    gload_lds16((char*)&smem[BUF][3][0] + ch0 * 16, Blo + gB0 + ko_); \
    gload_lds16((char*)&smem[BUF][3][0] + ch1 * 16, Blo + gB1 + ko_); }

    STAGE(0, 0);
    __syncthreads();
    int cur = 0;
    for (int ks = 0; ks < nK; ++ks) {
        if (ks + 1 < nK) STAGE(cur ^ 1, ks + 1);   // prefetch overlaps compute

        bf16x8 ah[4], al[4], bh[4], bl[4];
        #pragma unroll
        for (int f = 0; f < 4; ++f) {
            ah[f] = *(const bf16x8*)((const char*)&smem[cur][0][0] + offA[f]);
            al[f] = *(const bf16x8*)((const char*)&smem[cur][1][0] + offA[f]);
            bh[f] = *(const bf16x8*)((const char*)&smem[cur][2][0] + offB[f]);
            bl[f] = *(const bf16x8*)((const char*)&smem[cur][3][0] + offB[f]);
        }
        #pragma unroll
        for (int i = 0; i < 4; ++i)
            #pragma unroll
            for (int j = 0; j < 4; ++j) {
                acc[i][j] = __builtin_amdgcn_mfma_f32_16x16x32_bf16(al[i], bh[j], acc[i][j], 0, 0, 0);
                acc[i][j] = __builtin_amdgcn_mfma_f32_16x16x32_bf16(ah[i], bl[j], acc[i][j], 0, 0, 0);
                acc[i][j] = __builtin_amdgcn_mfma_f32_16x16x32_bf16(ah[i], bh[j], acc[i][j], 0, 0, 0);
            }
        __syncthreads();
        cur ^= 1;
    }
#undef STAGE

    // epilogue: C/D frag layout col=lane&15, row=(lane>>4)*4+reg  [m89-verified]
    const int rb = row0 + wr * 64;
    const int cb = col0 + wc * 64;
    #pragma unroll
    for (int i = 0; i < 4; ++i) {
        #pragma unroll
        for (int j = 0; j < 4; ++j) {
            const int c = cb + j * 16 + (lane & 15);
            const float bz = bias[c];
            #pragma unroll
            for (int rg = 0; rg < 4; ++rg) {
                const int r = rb + i * 16 + (lane >> 4) * 4 + rg;
                if (r < M) {
                    const float v = acc[i][j][rg] + bz;
                    if (WRITE_MODE == 0) {
                        const int sec = c >> 8;   // 0=q 1=k 2=v 3=s (uniform per tile)
                        if (sec == 0)      qs[(size_t)r * 512 + c] = v * SCALE_ATT;
                        else if (sec == 3) qs[(size_t)r * 512 + c - 512] = v;
                        else               kv[(size_t)r * 512 + c - 256] = (_Float16)v;
                    } else {
                        __hip_bfloat16 hi = __float2bfloat16(v);
                        Chi[(size_t)r * 256 + c] = hi;
                        Clo[(size_t)r * 256 + c] = __float2bfloat16(v - __bfloat162float(hi));
                    }
                }
            }
        }
    }
}

// ---------------- fused attention: block=node, wave-per-edge, 4-deep pipeline ----
// No-max softmax (alpha analytically bounded; fp32-safe, mathematically identical).
// WH==0: write h_hi/h_lo only. WH==1: last layer, write h fp32 only.
template <int WH>
__global__ __launch_bounds__(256) void node_attn_kernel(
        const float* __restrict__ qs, const _Float16* __restrict__ kv,
        const int* __restrict__ offsets,
        const int* __restrict__ esrc, const float* __restrict__ Wbeta,
        const float* __restrict__ ln_g, const float* __restrict__ ln_b,
        float* __restrict__ h_out,
        __hip_bfloat16* __restrict__ h_hi, __hip_bfloat16* __restrict__ h_lo) {
    const int n = blockIdx.x;
    const int t = threadIdx.x;
    const int lane = t & 63, wave = t >> 6;
    __shared__ int s_src[256];
    __shared__ float s_acc[4][256];
    __shared__ float s_s[4][8];
    __shared__ float red[8];
    __shared__ float s_beta;

    const float4 q4 = reinterpret_cast<const float4*>(qs + (size_t)n * 512)[lane];

    float ssum = 0.f;
    float4 accv = make_float4(0.f, 0.f, 0.f, 0.f);
    const int rs = offsets[n], re = offsets[n + 1];

#define LOADKV(KB, VB, J) { const half4* r_ = reinterpret_cast<const half4*>(kv + (size_t)s_src[(J)] * 512); \
                            KB = r_[lane]; VB = r_[64 + lane]; }
#define STEP(KB, VB) { \
    float p_ = q4.x * (float)KB.x + q4.y * (float)KB.y + q4.z * (float)KB.z + q4.w * (float)KB.w; \
    p_ += __shfl_xor(p_, 1, 8); p_ += __shfl_xor(p_, 2, 8); p_ += __shfl_xor(p_, 4, 8); \
    const float e_ = __expf(p_); \
    ssum += e_; \
    accv.x += e_ * (float)VB.x; \
    accv.y += e_ * (float)VB.y; \
    accv.z += e_ * (float)VB.z; \
    accv.w += e_ * (float)VB.w; }

    for (int base = rs; base < re; base += 256) {
        const int cnt = min(re - base, 256);
        if (t < cnt) s_src[t] = esrc[base + t];
        __syncthreads();

        half4 k0, v0, k1, v1, k2, v2, k3, v3;
        int j = wave;
        if (j      < cnt) LOADKV(k0, v0, j);
        if (j + 4  < cnt) LOADKV(k1, v1, j + 4);
        if (j + 8  < cnt) LOADKV(k2, v2, j + 8);
        if (j + 12 < cnt) LOADKV(k3, v3, j + 12);

        while (j < cnt) {
            STEP(k0, v0); if (j + 16 < cnt) LOADKV(k0, v0, j + 16); j += 4;
            if (j >= cnt) break;
            STEP(k1, v1); if (j + 16 < cnt) LOADKV(k1, v1, j + 16); j += 4;
            if (j >= cnt) break;
            STEP(k2, v2); if (j + 16 < cnt) LOADKV(k2, v2, j + 16); j += 4;
            if (j >= cnt) break;
            STEP(k3, v3); if (j + 16 < cnt) LOADKV(k3, v3, j + 16); j += 4;
        }
        __syncthreads();
    }
#undef LOADKV
#undef STEP

    // merge 4 per-wave partials (plain sums — no max tracking)
    *reinterpret_cast<float4*>(&s_acc[wave][lane * 4]) = accv;
    if ((lane & 7) == 0) s_s[wave][lane >> 3] = ssum;
    __syncthreads();

    const int hd = t >> 5;
    const float den = s_s[0][hd] + s_s[1][hd] + s_s[2][hd] + s_s[3][hd];
    const float out = (s_acc[0][t] + s_acc[1][t] + s_acc[2][t] + s_acc[3][t]) / (den + 1e-16f);

    const float xr = qs[(size_t)n * 512 + 256 + t];

    float bl = out * (Wbeta[t] + Wbeta[512 + t]) + xr * (Wbeta[256 + t] - Wbeta[512 + t]);
    #pragma unroll
    for (int o = 32; o >= 1; o >>= 1) bl += __shfl_xor(bl, o, 64);
    if ((t & 63) == 0) red[wave] = bl;
    __syncthreads();
    if (t == 0) {
        float v = red[0] + red[1] + red[2] + red[3];
        s_beta = 1.f / (1.f + __expf(-v));
    }
    __syncthreads();
    const float beta = s_beta;
    const float hn = beta * xr + (1.f - beta) * out;

    float r1 = hn;
    #pragma unroll
    for (int o = 32; o >= 1; o >>= 1) r1 += __shfl_xor(r1, o, 64);
    if ((t & 63) == 0) red[4 + wave] = r1;
    __syncthreads();
    const float mu = (red[4] + red[5] + red[6] + red[7]) * (1.f / 256.f);
    const float d = hn - mu;
    float r2 = d * d;
    #pragma unroll
    for (int o = 32; o >= 1; o >>= 1) r2 += __shfl_xor(r2, o, 64);
    if ((t & 63) == 0) red[wave] = r2;
    __syncthreads();
    const float var = (red[0] + red[1] + red[2] + red[3]) * (1.f / 256.f);

    float y = d * rsqrtf(var + 1e-5f) * ln_g[t] + ln_b[t];
    y = fmaxf(y, 0.f);
    if (WH == 1) {
        h_out[(size_t)n * 256 + t] = y;
    } else {
        __hip_bfloat16 hi = __float2bfloat16(y);
        h_hi[(size_t)n * 256 + t] = hi;
        h_lo[(size_t)n * 256 + t] = __float2bfloat16(y - __bfloat162float(hi));
    }
}

// ---------------- mean pool (batch sorted): 32 nodes/block, register-staged ----
constexpr int POOL_N = 32;
__global__ __launch_bounds__(256) void pool_kernel(const float* __restrict__ h,
                                                   const int* __restrict__ batch, int Nn,
                                                   float* __restrict__ sums,
                                                   float* __restrict__ cnt) {
    const int start = blockIdx.x * POOL_N;
    const int end = min(start + POOL_N, Nn);
    if (start >= end) return;
    const int t = threadIdx.x;

    float val[POOL_N];
    #pragma unroll
    for (int i = 0; i < POOL_N; ++i) {
        const int n = start + i;
        val[i] = (n < end) ? h[(size_t)n * 256 + t] : 0.f;
    }

    int cur = batch[start];
    float run = 0.f;
    int c = 0;
    #pragma unroll
    for (int i = 0; i < POOL_N; ++i) {
        const int n = start + i;
        if (n >= end) break;
        const int g = batch[n];
        if (g != cur) {
            atomicAdd(&sums[(size_t)cur * 256 + t], run);
            if (t == 0) atomicAdd(&cnt[cur], (float)c);
            run = 0.f; c = 0; cur = g;
        }
        run += val[i];
        ++c;
    }
    atomicAdd(&sums[(size_t)cur * 256 + t], run);
    if (t == 0) atomicAdd(&cnt[cur], (float)c);
}

__global__ __launch_bounds__(128) void final_kernel(const float* __restrict__ sums,
                                                    const float* __restrict__ cnt,
                                                    const float* __restrict__ Wf,
                                                    const float* __restrict__ bf,
                                                    float* __restrict__ out) {
    const int g = blockIdx.x;
    const int t = threadIdx.x;
    __shared__ float p[256];
    const float c = fmaxf(cnt[g], 1.f);
    for (int i = t; i < 256; i += 128) p[i] = sums[(size_t)g * 256 + i] / c;
    __syncthreads();
    float acc = bf[t];
    #pragma unroll 4
    for (int k = 0; k < 256; ++k) acc += p[k] * Wf[k * 128 + t];
    out[(size_t)g * 128 + t] = acc;
}

// ---------------- launcher ----------------
extern "C" void kernel_launch(void* const* d_in, const int* in_sizes, int n_in,
                              void* d_out, int out_size, void* d_ws, size_t ws_size,
                              hipStream_t stream) {
    const float* x       = (const float*)d_in[0];
    const int*   eidx    = (const int*)  d_in[1];
    const int*   batch   = (const int*)  d_in[2];
    const float* W_init  = (const float*)d_in[3];
    const float* b_init  = (const float*)d_in[4];
    const float* Wq      = (const float*)d_in[5];
    const float* bq      = (const float*)d_in[6];
    const float* Wk      = (const float*)d_in[7];
    const float* bk      = (const float*)d_in[8];
    const float* Wv      = (const float*)d_in[9];
    const float* bv      = (const float*)d_in[10];
    const float* Ws      = (const float*)d_in[11];
    const float* bs      = (const float*)d_in[12];
    const float* Wbeta   = (const float*)d_in[13];
    const float* ln_g    = (const float*)d_in[14];
    const float* ln_b    = (const float*)d_in[15];
    const float* W_final = (const float*)d_in[16];
    const float* b_final = (const float*)d_in[17];

    const int* e_src = eidx;
    const int* e_dst = eidx + E_EDGES;

    char* p = (char*)d_ws;
    auto alloc = [&](size_t bytes) {
        void* r = (void*)p;
        p += (bytes + 255) & ~(size_t)255;
        return r;
    };
    float* h      = (float*)alloc((size_t)M_PAD * 256 * 4);
    float* qs     = (float*)alloc((size_t)N_NODES * 512 * 4);
    _Float16* kv  = (_Float16*)alloc((size_t)N_NODES * 512 * 2);
    __hip_bfloat16* h_hi = (__hip_bfloat16*)alloc((size_t)M_PAD * 256 * 2);
    __hip_bfloat16* h_lo = (__hip_bfloat16*)alloc((size_t)M_PAD * 256 * 2);
    __hip_bfloat16* x_hi = (__hip_bfloat16*)alloc((size_t)M_PAD * 128 * 2);
    __hip_bfloat16* x_lo = (__hip_bfloat16*)alloc((size_t)M_PAD * 128 * 2);
    __hip_bfloat16* Wt_hi = (__hip_bfloat16*)alloc((size_t)LAYERS * 1024 * 256 * 2);
    __hip_bfloat16* Wt_lo = (__hip_bfloat16*)alloc((size_t)LAYERS * 1024 * 256 * 2);
    __hip_bfloat16* Wi_hi = (__hip_bfloat16*)alloc((size_t)256 * 128 * 2);
    __hip_bfloat16* Wi_lo = (__hip_bfloat16*)alloc((size_t)256 * 128 * 2);
    float* bcat   = (float*)alloc((size_t)LAYERS * 1024 * 4);
    int* counts   = (int*)alloc((size_t)N_NODES * 4);
    int* offsets  = (int*)alloc((size_t)(N_NODES + 1) * 4);
    int* cursor   = (int*)alloc((size_t)N_NODES * 4);
    int* esrc     = (int*)alloc((size_t)E_EDGES * 4);
    float* sums   = (float*)alloc((size_t)G_GRAPHS * 256 * 4);
    float* cnt    = (float*)alloc((size_t)G_GRAPHS * 4);

    hipMemsetAsync(counts, 0, sizeof(int) * N_NODES, stream);
    hipMemsetAsync(cursor, 0, sizeof(int) * N_NODES, stream);
    hipMemsetAsync(sums, 0, sizeof(float) * G_GRAPHS * 256, stream);
    hipMemsetAsync(cnt, 0, sizeof(float) * G_GRAPHS, stream);

    count_kernel<<<(E_EDGES + 255) / 256, 256, 0, stream>>>(e_dst, E_EDGES, counts);
    scan_kernel<<<1, 1024, 0, stream>>>(counts, offsets, N_NODES);
    scatter_kernel<<<(E_EDGES + 255) / 256, 256, 0, stream>>>(e_src, e_dst, E_EDGES,
                                                              offsets, cursor, esrc);

    wt_layers<<<dim3(64, 4, LAYERS), 256, 0, stream>>>(Wq, Wk, Wv, Ws, Wt_hi, Wt_lo);
    wt_init<<<32, 256, 0, stream>>>(W_init, Wi_hi, Wi_lo);
    bias_cat<<<LAYERS * 4, 256, 0, stream>>>(bq, bk, bv, bs, bcat);
    conv_hi_lo<<<(N_NODES * 128 + 255) / 256, 256, 0, stream>>>(x, N_NODES * 128, x_hi, x_lo);

    const int rowTiles = M_PAD / 128;   // 157

    gemm_mfma<1><<<dim3(2, rowTiles), 256, 0, stream>>>(
        x_hi, x_lo, Wi_hi, Wi_lo, b_init, N_NODES, 128,
        nullptr, nullptr, h_hi, h_lo);

    for (int l = 0; l < LAYERS; ++l) {
        gemm_mfma<0><<<dim3(8, rowTiles), 256, 0, stream>>>(
            h_hi, h_lo,
            Wt_hi + (size_t)l * 1024 * 256, Wt_lo + (size_t)l * 1024 * 256,
            bcat + (size_t)l * 1024, N_NODES, 256,
            qs, kv, nullptr, nullptr);

        if (l < LAYERS - 1) {
            node_attn_kernel<0><<<N_NODES, 256, 0, stream>>>(
                qs, kv, offsets, esrc,
                Wbeta + (size_t)l * 768,
                ln_g + (size_t)l * 256, ln_b + (size_t)l * 256,
                nullptr, h_hi, h_lo);
        } else {
            node_attn_kernel<1><<<N_NODES, 256, 0, stream>>>(
                qs, kv, offsets, esrc,
                Wbeta + (size_t)l * 768,
                ln_g + (size_t)l * 256, ln_b + (size_t)l * 256,
                h, nullptr, nullptr);
        }
    }

    pool_kernel<<<(N_NODES + POOL_N - 1) / POOL_N, 256, 0, stream>>>(h, batch, N_NODES, sums, cnt);
    final_kernel<<<G_GRAPHS, 128, 0, stream>>>(sums, cnt, W_final, b_final, (float*)d_out);
}

// Round 11
// 1078.303 us; speedup vs baseline: 1.4453x; 1.0413x over previous
//
#include <hip/hip_runtime.h>
#include <hip/hip_bf16.h>
#include <math.h>

// ---------------- problem constants ----------------
constexpr int N_NODES  = 20000;
constexpr int M_PAD    = 20096;   // 157 * 128 row tiles
constexpr int E_EDGES  = 320000;
constexpr int G_GRAPHS = 64;
constexpr int F_IN     = 128;
constexpr int H_DIM    = 256;
constexpr int LAYERS   = 8;
constexpr float SCALE_ATT = 0.17677669529663687f; // 1/sqrt(32)

typedef __attribute__((ext_vector_type(8))) short bf16x8;
typedef __attribute__((ext_vector_type(4))) float f32x4;
typedef _Float16 half4 __attribute__((ext_vector_type(4)));
typedef unsigned int u32;

__device__ static inline void gload_lds16(void* lds, const void* g) {
    __builtin_amdgcn_global_load_lds((const __attribute__((address_space(1))) u32*)g,
                                     (__attribute__((address_space(3))) u32*)lds, 16, 0, 0);
}

// ---------------- CSR build ----------------
__global__ void count_kernel(const int* __restrict__ dst, int E, int* __restrict__ counts) {
    int i = blockIdx.x * blockDim.x + threadIdx.x;
    if (i < E) atomicAdd(&counts[dst[i]], 1);
}

// wave-shfl based scan: 1024 threads = 16 waves
__global__ __launch_bounds__(1024) void scan_kernel(const int* __restrict__ counts,
                                                    int* __restrict__ offsets, int n) {
    __shared__ int wsum[16];
    __shared__ int carry_s;
    const int t = threadIdx.x;
    const int lane = t & 63, w = t >> 6;
    if (t == 0) { carry_s = 0; offsets[0] = 0; }
    __syncthreads();
    for (int base = 0; base < n; base += 1024) {
        const int i = base + t;
        const int v = (i < n) ? counts[i] : 0;
        int s = v;
        #pragma unroll
        for (int off = 1; off < 64; off <<= 1) {
            int x = __shfl_up(s, off, 64);
            if (lane >= off) s += x;
        }
        if (lane == 63) wsum[w] = s;
        __syncthreads();
        if (w == 0) {
            int x = (lane < 16) ? wsum[lane] : 0;
            #pragma unroll
            for (int off = 1; off < 16; off <<= 1) {
                int y = __shfl_up(x, off, 64);
                if (lane >= off) x += y;
            }
            if (lane < 16) wsum[lane] = x;
        }
        __syncthreads();
        const int wadd = (w > 0) ? wsum[w - 1] : 0;
        const int inc = carry_s + wadd + s;
        if (i < n) offsets[i + 1] = inc;
        __syncthreads();
        if (t == 1023) carry_s = inc;
        __syncthreads();
    }
}

__global__ void scatter_kernel(const int* __restrict__ src, const int* __restrict__ dst, int E,
                               const int* __restrict__ offsets, int* __restrict__ cursor,
                               int* __restrict__ esrc) {
    int i = blockIdx.x * blockDim.x + threadIdx.x;
    if (i < E) {
        int d = dst[i];
        int pos = atomicAdd(&cursor[d], 1);
        esrc[offsets[d] + pos] = src[i];
    }
}

// ---------------- weight transpose + hi/lo bf16 split ----------------
__global__ __launch_bounds__(256) void wt_layers(
        const float* __restrict__ Wq, const float* __restrict__ Wk,
        const float* __restrict__ Wv, const float* __restrict__ Ws,
        __hip_bfloat16* __restrict__ Whi, __hip_bfloat16* __restrict__ Wlo) {
    const int l = blockIdx.z, z = blockIdx.y;
    const int tk = (blockIdx.x & 7) * 32;
    const int tn = (blockIdx.x >> 3) * 32;
    const float* src = (z == 0 ? Wq : z == 1 ? Wk : z == 2 ? Wv : Ws) + (size_t)l * 65536;
    __shared__ float tile[32][33];
    const int tx = threadIdx.x & 31, ty = threadIdx.x >> 5;
    #pragma unroll
    for (int p = 0; p < 4; ++p)
        tile[ty + p * 8][tx] = src[(size_t)(tk + ty + p * 8) * 256 + tn + tx];
    __syncthreads();
    #pragma unroll
    for (int p = 0; p < 4; ++p) {
        int n = tn + ty + p * 8;
        float v = tile[tx][ty + p * 8];
        size_t o = ((size_t)l * 1024 + z * 256 + n) * 256 + tk + tx;
        __hip_bfloat16 hi = __float2bfloat16(v);
        Whi[o] = hi;
        Wlo[o] = __float2bfloat16(v - __bfloat162float(hi));
    }
}

__global__ __launch_bounds__(256) void wt_init(const float* __restrict__ Wi,
        __hip_bfloat16* __restrict__ Whi, __hip_bfloat16* __restrict__ Wlo) {
    const int tk = (blockIdx.x & 3) * 32;
    const int tn = (blockIdx.x >> 2) * 32;
    __shared__ float tile[32][33];
    const int tx = threadIdx.x & 31, ty = threadIdx.x >> 5;
    #pragma unroll
    for (int p = 0; p < 4; ++p)
        tile[ty + p * 8][tx] = Wi[(size_t)(tk + ty + p * 8) * 256 + tn + tx];
    __syncthreads();
    #pragma unroll
    for (int p = 0; p < 4; ++p) {
        int n = tn + ty + p * 8;
        float v = tile[tx][ty + p * 8];
        size_t o = (size_t)n * 128 + tk + tx;
        __hip_bfloat16 hi = __float2bfloat16(v);
        Whi[o] = hi;
        Wlo[o] = __float2bfloat16(v - __bfloat162float(hi));
    }
}

__global__ __launch_bounds__(256) void bias_cat(const float* __restrict__ bq,
        const float* __restrict__ bk, const float* __restrict__ bv,
        const float* __restrict__ bs, float* __restrict__ bcat) {
    int l = blockIdx.x >> 2, z = blockIdx.x & 3;
    const float* b = (z == 0 ? bq : z == 1 ? bk : z == 2 ? bv : bs) + (size_t)l * 256;
    bcat[(size_t)l * 1024 + z * 256 + threadIdx.x] = b[threadIdx.x];
}

__global__ void conv_hi_lo(const float* __restrict__ src, int n,
                           __hip_bfloat16* __restrict__ hi, __hip_bfloat16* __restrict__ lo) {
    int i = blockIdx.x * blockDim.x + threadIdx.x;
    if (i < n) {
        float v = src[i];
        __hip_bfloat16 h = __float2bfloat16(v);
        hi[i] = h;
        lo[i] = __float2bfloat16(v - __bfloat162float(h));
    }
}

// ---------------- split-precision bf16 MFMA GEMM (LDS dbuf, counted vmcnt) ----
// T4 pattern: raw s_barrier + s_waitcnt vmcnt(8) — the 8 prefetch loads stay in
// flight across the barrier; only the current buffer's (older) 8 are drained.
// WRITE_MODE 0: qs (fp32 q*SCALE | s) + kv (fp16 k|v). WRITE_MODE 1: bf16 hi/lo.
template <int WRITE_MODE>
__global__ __launch_bounds__(256) void gemm_mfma(
        const __hip_bfloat16* __restrict__ Ahi, const __hip_bfloat16* __restrict__ Alo,
        const __hip_bfloat16* __restrict__ Bhi, const __hip_bfloat16* __restrict__ Blo,
        const float* __restrict__ bias, int M, int K,
        float* __restrict__ qs, _Float16* __restrict__ kv,
        __hip_bfloat16* __restrict__ Chi, __hip_bfloat16* __restrict__ Clo) {
    const int t = threadIdx.x;
    const int lane = t & 63, wave = t >> 6;

    // bijective XCD chunk swizzle (m204)
    const int nwg = gridDim.x * gridDim.y;
    const int lid = blockIdx.y * gridDim.x + blockIdx.x;
    const int qch = nwg >> 3, rch = nwg & 7;
    const int xcd = lid & 7, pos = lid >> 3;
    const int swz = (xcd < rch ? xcd * (qch + 1) : rch * (qch + 1) + (xcd - rch) * qch) + pos;
    const int row0 = (swz / gridDim.x) * 128;
    const int col0 = (swz % gridDim.x) * 128;

    __shared__ __align__(16) __hip_bfloat16 smem[2][4][4096];   // 64 KB

    const int ch0 = wave * 64 + lane;
    const int ch1 = ch0 + 256;
    const int rA0 = ch0 >> 2, cA0 = (ch0 & 3) ^ ((rA0 >> 1) & 3);
    const int rA1 = ch1 >> 2, cA1 = (ch1 & 3) ^ ((rA1 >> 1) & 3);
    const size_t gOff0 = (size_t)rA0 * K + cA0 * 8;
    const size_t gOff1 = (size_t)rA1 * K + cA1 * 8;
    const size_t gA0 = (size_t)row0 * K + gOff0, gA1 = (size_t)row0 * K + gOff1;
    const size_t gB0 = (size_t)col0 * K + gOff0, gB1 = (size_t)col0 * K + gOff1;

    const int wr = wave >> 1, wc = wave & 1;
    int offA[4], offB[4];
    #pragma unroll
    for (int f = 0; f < 4; ++f) {
        int ra = wr * 64 + f * 16 + (lane & 15);
        offA[f] = ra * 64 + (((lane >> 4) ^ ((ra >> 1) & 3)) << 4);
        int rb = wc * 64 + f * 16 + (lane & 15);
        offB[f] = rb * 64 + (((lane >> 4) ^ ((rb >> 1) & 3)) << 4);
    }

    f32x4 acc[4][4] = {};
    const int nK = K >> 5;

#define STAGE(BUF, KS) { const size_t ko_ = (size_t)(KS) * 32; \
    gload_lds16((char*)&smem[BUF][0][0] + ch0 * 16, Ahi + gA0 + ko_); \
    gload_lds16((char*)&smem[BUF][0][0] + ch1 * 16, Ahi + gA1 + ko_); \
    gload_lds16((char*)&smem[BUF][1][0] + ch0 * 16, Alo + gA0 + ko_); \
    gload_lds16((char*)&smem[BUF][1][0] + ch1 * 16, Alo + gA1 + ko_); \
    gload_lds16((char*)&smem[BUF][2][0] + ch0 * 16, Bhi + gB0 + ko_); \
    gload_lds16((char*)&smem[BUF][2][0] + ch1 * 16, Bhi + gB1 + ko_); \
    gload_lds16((char*)&smem[BUF][3][0] + ch0 * 16, Blo + gB0 + ko_); \
    gload_lds16((char*)&smem[BUF][3][0] + ch1 * 16, Blo + gB1 + ko_); }

    STAGE(0, 0);                                  // 8 loads in flight
    int cur = 0;
    for (int ks = 0; ks < nK; ++ks) {
        if (ks + 1 < nK) {
            STAGE(cur ^ 1, ks + 1);               // +8 newer loads (16 total)
            asm volatile("s_waitcnt vmcnt(8)" ::: "memory");   // cur's 8 done; prefetch flying
        } else {
            asm volatile("s_waitcnt vmcnt(0)" ::: "memory");
        }
        __builtin_amdgcn_s_barrier();             // all waves' cur-chunk loads done
        __builtin_amdgcn_sched_barrier(0);

        bf16x8 ah[4], al[4], bh[4], bl[4];
        #pragma unroll
        for (int f = 0; f < 4; ++f) {
            ah[f] = *(const bf16x8*)((const char*)&smem[cur][0][0] + offA[f]);
            al[f] = *(const bf16x8*)((const char*)&smem[cur][1][0] + offA[f]);
            bh[f] = *(const bf16x8*)((const char*)&smem[cur][2][0] + offB[f]);
            bl[f] = *(const bf16x8*)((const char*)&smem[cur][3][0] + offB[f]);
        }
        #pragma unroll
        for (int i = 0; i < 4; ++i)
            #pragma unroll
            for (int j = 0; j < 4; ++j) {
                acc[i][j] = __builtin_amdgcn_mfma_f32_16x16x32_bf16(al[i], bh[j], acc[i][j], 0, 0, 0);
                acc[i][j] = __builtin_amdgcn_mfma_f32_16x16x32_bf16(ah[i], bl[j], acc[i][j], 0, 0, 0);
                acc[i][j] = __builtin_amdgcn_mfma_f32_16x16x32_bf16(ah[i], bh[j], acc[i][j], 0, 0, 0);
            }
        __builtin_amdgcn_sched_barrier(0);
        __builtin_amdgcn_s_barrier();             // cur fully read before next overwrite
        cur ^= 1;
    }
#undef STAGE

    // epilogue: C/D frag layout col=lane&15, row=(lane>>4)*4+reg  [m89-verified]
    const int rb = row0 + wr * 64;
    const int cb = col0 + wc * 64;
    #pragma unroll
    for (int i = 0; i < 4; ++i) {
        #pragma unroll
        for (int j = 0; j < 4; ++j) {
            const int c = cb + j * 16 + (lane & 15);
            const float bz = bias[c];
            #pragma unroll
            for (int rg = 0; rg < 4; ++rg) {
                const int r = rb + i * 16 + (lane >> 4) * 4 + rg;
                if (r < M) {
                    const float v = acc[i][j][rg] + bz;
                    if (WRITE_MODE == 0) {
                        const int sec = c >> 8;   // 0=q 1=k 2=v 3=s (uniform per tile)
                        if (sec == 0)      qs[(size_t)r * 512 + c] = v * SCALE_ATT;
                        else if (sec == 3) qs[(size_t)r * 512 + c - 512] = v;
                        else               kv[(size_t)r * 512 + c - 256] = (_Float16)v;
                    } else {
                        __hip_bfloat16 hi = __float2bfloat16(v);
                        Chi[(size_t)r * 256 + c] = hi;
                        Clo[(size_t)r * 256 + c] = __float2bfloat16(v - __bfloat162float(hi));
                    }
                }
            }
        }
    }
}

// ---------------- fused attention: ONE WAVE PER NODE, no LDS, no barriers ----
// Lane holds channels 4*lane..4*lane+3 (head = lane>>3). No-max softmax.
// 4-deep k/v register pipeline; indices register-broadcast via __shfl.
// WH==0: write h_hi/h_lo only. WH==1: last layer, write h fp32 only.
template <int WH>
__global__ __launch_bounds__(256) void node_attn_kernel(
        const float* __restrict__ qs, const _Float16* __restrict__ kv,
        const int* __restrict__ offsets,
        const int* __restrict__ esrc, const float* __restrict__ Wbeta,
        const float* __restrict__ ln_g, const float* __restrict__ ln_b,
        float* __restrict__ h_out,
        __hip_bfloat16* __restrict__ h_hi, __hip_bfloat16* __restrict__ h_lo) {
    const int t = threadIdx.x;
    const int lane = t & 63, wave = t >> 6;
    const int n = blockIdx.x * 4 + wave;
    if (n >= N_NODES) return;

    const float4 q4 = reinterpret_cast<const float4*>(qs + (size_t)n * 512)[lane];

    float ssum = 0.f;
    float ax = 0.f, ay = 0.f, az = 0.f, aw = 0.f;
    const int rs = offsets[n], re = offsets[n + 1];

#define LOADKV(KB, VB, S) { const half4* r_ = reinterpret_cast<const half4*>(kv + (size_t)(S) * 512); \
                            KB = r_[lane]; VB = r_[64 + lane]; }
#define STEP(KB, VB) { \
    float p_ = q4.x * (float)KB.x + q4.y * (float)KB.y + q4.z * (float)KB.z + q4.w * (float)KB.w; \
    p_ += __shfl_xor(p_, 1, 8); p_ += __shfl_xor(p_, 2, 8); p_ += __shfl_xor(p_, 4, 8); \
    const float e_ = __expf(p_); \
    ssum += e_; \
    ax += e_ * (float)VB.x; \
    ay += e_ * (float)VB.y; \
    az += e_ * (float)VB.z; \
    aw += e_ * (float)VB.w; }

    for (int base = rs; base < re; base += 64) {
        const int cnt = min(re - base, 64);
        const int idx = (lane < cnt) ? esrc[base + lane] : 0;

        half4 k0, v0, k1, v1, k2, v2, k3, v3;
        if (0 < cnt) LOADKV(k0, v0, __shfl(idx, 0));
        if (1 < cnt) LOADKV(k1, v1, __shfl(idx, 1));
        if (2 < cnt) LOADKV(k2, v2, __shfl(idx, 2));
        if (3 < cnt) LOADKV(k3, v3, __shfl(idx, 3));

        int j = 0;
        while (j < cnt) {
            STEP(k0, v0); if (j + 4 < cnt) LOADKV(k0, v0, __shfl(idx, j + 4)); ++j;
            if (j >= cnt) break;
            STEP(k1, v1); if (j + 4 < cnt) LOADKV(k1, v1, __shfl(idx, j + 4)); ++j;
            if (j >= cnt) break;
            STEP(k2, v2); if (j + 4 < cnt) LOADKV(k2, v2, __shfl(idx, j + 4)); ++j;
            if (j >= cnt) break;
            STEP(k3, v3); if (j + 4 < cnt) LOADKV(k3, v3, __shfl(idx, j + 4)); ++j;
        }
    }
#undef LOADKV
#undef STEP

    const float inv = 1.f / (ssum + 1e-16f);
    const float ox = ax * inv, oy = ay * inv, oz = az * inv, ow = aw * inv;

    const float4 xr = reinterpret_cast<const float4*>(qs + (size_t)n * 512 + 256)[lane];
    const float4 w0 = reinterpret_cast<const float4*>(Wbeta)[lane];
    const float4 w1 = reinterpret_cast<const float4*>(Wbeta + 256)[lane];
    const float4 w2 = reinterpret_cast<const float4*>(Wbeta + 512)[lane];

    float bl = ox * (w0.x + w2.x) + xr.x * (w1.x - w2.x)
             + oy * (w0.y + w2.y) + xr.y * (w1.y - w2.y)
             + oz * (w0.z + w2.z) + xr.z * (w1.z - w2.z)
             + ow * (w0.w + w2.w) + xr.w * (w1.w - w2.w);
    #pragma unroll
    for (int o = 32; o >= 1; o >>= 1) bl += __shfl_xor(bl, o, 64);
    const float beta = 1.f / (1.f + __expf(-bl));

    const float hx = beta * xr.x + (1.f - beta) * ox;
    const float hy = beta * xr.y + (1.f - beta) * oy;
    const float hz = beta * xr.z + (1.f - beta) * oz;
    const float hw = beta * xr.w + (1.f - beta) * ow;

    float s1 = hx + hy + hz + hw;
    #pragma unroll
    for (int o = 32; o >= 1; o >>= 1) s1 += __shfl_xor(s1, o, 64);
    const float mu = s1 * (1.f / 256.f);

    const float dx = hx - mu, dy = hy - mu, dz = hz - mu, dw = hw - mu;
    float s2 = dx * dx + dy * dy + dz * dz + dw * dw;
    #pragma unroll
    for (int o = 32; o >= 1; o >>= 1) s2 += __shfl_xor(s2, o, 64);
    const float rstd = rsqrtf(s2 * (1.f / 256.f) + 1e-5f);

    const float4 g4 = reinterpret_cast<const float4*>(ln_g)[lane];
    const float4 b4 = reinterpret_cast<const float4*>(ln_b)[lane];
    float4 y;
    y.x = fmaxf(dx * rstd * g4.x + b4.x, 0.f);
    y.y = fmaxf(dy * rstd * g4.y + b4.y, 0.f);
    y.z = fmaxf(dz * rstd * g4.z + b4.z, 0.f);
    y.w = fmaxf(dw * rstd * g4.w + b4.w, 0.f);

    if (WH == 1) {
        reinterpret_cast<float4*>(h_out + (size_t)n * 256)[lane] = y;
    } else {
        ushort4 uhi, ulo;
        __hip_bfloat16 h0 = __float2bfloat16(y.x);
        __hip_bfloat16 h1 = __float2bfloat16(y.y);
        __hip_bfloat16 h2 = __float2bfloat16(y.z);
        __hip_bfloat16 h3 = __float2bfloat16(y.w);
        __hip_bfloat16 l0 = __float2bfloat16(y.x - __bfloat162float(h0));
        __hip_bfloat16 l1 = __float2bfloat16(y.y - __bfloat162float(h1));
        __hip_bfloat16 l2 = __float2bfloat16(y.z - __bfloat162float(h2));
        __hip_bfloat16 l3 = __float2bfloat16(y.w - __bfloat162float(h3));
        uhi.x = *(unsigned short*)&h0; uhi.y = *(unsigned short*)&h1;
        uhi.z = *(unsigned short*)&h2; uhi.w = *(unsigned short*)&h3;
        ulo.x = *(unsigned short*)&l0; ulo.y = *(unsigned short*)&l1;
        ulo.z = *(unsigned short*)&l2; ulo.w = *(unsigned short*)&l3;
        reinterpret_cast<ushort4*>(h_hi + (size_t)n * 256)[lane] = uhi;
        reinterpret_cast<ushort4*>(h_lo + (size_t)n * 256)[lane] = ulo;
    }
}

// ---------------- mean pool (batch sorted): 32 nodes/block, register-staged ----
constexpr int POOL_N = 32;
__global__ __launch_bounds__(256) void pool_kernel(const float* __restrict__ h,
                                                   const int* __restrict__ batch, int Nn,
                                                   float* __restrict__ sums,
                                                   float* __restrict__ cnt) {
    const int start = blockIdx.x * POOL_N;
    const int end = min(start + POOL_N, Nn);
    if (start >= end) return;
    const int t = threadIdx.x;

    float val[POOL_N];
    #pragma unroll
    for (int i = 0; i < POOL_N; ++i) {
        const int n = start + i;
        val[i] = (n < end) ? h[(size_t)n * 256 + t] : 0.f;
    }

    int cur = batch[start];
    float run = 0.f;
    int c = 0;
    #pragma unroll
    for (int i = 0; i < POOL_N; ++i) {
        const int n = start + i;
        if (n >= end) break;
        const int g = batch[n];
        if (g != cur) {
            atomicAdd(&sums[(size_t)cur * 256 + t], run);
            if (t == 0) atomicAdd(&cnt[cur], (float)c);
            run = 0.f; c = 0; cur = g;
        }
        run += val[i];
        ++c;
    }
    atomicAdd(&sums[(size_t)cur * 256 + t], run);
    if (t == 0) atomicAdd(&cnt[cur], (float)c);
}

__global__ __launch_bounds__(128) void final_kernel(const float* __restrict__ sums,
                                                    const float* __restrict__ cnt,
                                                    const float* __restrict__ Wf,
                                                    const float* __restrict__ bf,
                                                    float* __restrict__ out) {
    const int g = blockIdx.x;
    const int t = threadIdx.x;
    __shared__ float p[256];
    const float c = fmaxf(cnt[g], 1.f);
    for (int i = t; i < 256; i += 128) p[i] = sums[(size_t)g * 256 + i] / c;
    __syncthreads();
    float acc = bf[t];
    #pragma unroll 4
    for (int k = 0; k < 256; ++k) acc += p[k] * Wf[k * 128 + t];
    out[(size_t)g * 128 + t] = acc;
}

// ---------------- launcher ----------------
extern "C" void kernel_launch(void* const* d_in, const int* in_sizes, int n_in,
                              void* d_out, int out_size, void* d_ws, size_t ws_size,
                              hipStream_t stream) {
    const float* x       = (const float*)d_in[0];
    const int*   eidx    = (const int*)  d_in[1];
    const int*   batch   = (const int*)  d_in[2];
    const float* W_init  = (const float*)d_in[3];
    const float* b_init  = (const float*)d_in[4];
    const float* Wq      = (const float*)d_in[5];
    const float* bq      = (const float*)d_in[6];
    const float* Wk      = (const float*)d_in[7];
    const float* bk      = (const float*)d_in[8];
    const float* Wv      = (const float*)d_in[9];
    const float* bv      = (const float*)d_in[10];
    const float* Ws      = (const float*)d_in[11];
    const float* bs      = (const float*)d_in[12];
    const float* Wbeta   = (const float*)d_in[13];
    const float* ln_g    = (const float*)d_in[14];
    const float* ln_b    = (const float*)d_in[15];
    const float* W_final = (const float*)d_in[16];
    const float* b_final = (const float*)d_in[17];

    const int* e_src = eidx;
    const int* e_dst = eidx + E_EDGES;

    char* p = (char*)d_ws;
    auto alloc = [&](size_t bytes) {
        void* r = (void*)p;
        p += (bytes + 255) & ~(size_t)255;
        return r;
    };
    float* h      = (float*)alloc((size_t)M_PAD * 256 * 4);
    float* qs     = (float*)alloc((size_t)N_NODES * 512 * 4);
    _Float16* kv  = (_Float16*)alloc((size_t)N_NODES * 512 * 2);
    __hip_bfloat16* h_hi = (__hip_bfloat16*)alloc((size_t)M_PAD * 256 * 2);
    __hip_bfloat16* h_lo = (__hip_bfloat16*)alloc((size_t)M_PAD * 256 * 2);
    __hip_bfloat16* x_hi = (__hip_bfloat16*)alloc((size_t)M_PAD * 128 * 2);
    __hip_bfloat16* x_lo = (__hip_bfloat16*)alloc((size_t)M_PAD * 128 * 2);
    __hip_bfloat16* Wt_hi = (__hip_bfloat16*)alloc((size_t)LAYERS * 1024 * 256 * 2);
    __hip_bfloat16* Wt_lo = (__hip_bfloat16*)alloc((size_t)LAYERS * 1024 * 256 * 2);
    __hip_bfloat16* Wi_hi = (__hip_bfloat16*)alloc((size_t)256 * 128 * 2);
    __hip_bfloat16* Wi_lo = (__hip_bfloat16*)alloc((size_t)256 * 128 * 2);
    float* bcat   = (float*)alloc((size_t)LAYERS * 1024 * 4);
    int* counts   = (int*)alloc((size_t)N_NODES * 4);
    int* offsets  = (int*)alloc((size_t)(N_NODES + 1) * 4);
    int* cursor   = (int*)alloc((size_t)N_NODES * 4);
    int* esrc     = (int*)alloc((size_t)E_EDGES * 4);
    float* sums   = (float*)alloc((size_t)G_GRAPHS * 256 * 4);
    float* cnt    = (float*)alloc((size_t)G_GRAPHS * 4);

    hipMemsetAsync(counts, 0, sizeof(int) * N_NODES, stream);
    hipMemsetAsync(cursor, 0, sizeof(int) * N_NODES, stream);
    hipMemsetAsync(sums, 0, sizeof(float) * G_GRAPHS * 256, stream);
    hipMemsetAsync(cnt, 0, sizeof(float) * G_GRAPHS, stream);

    count_kernel<<<(E_EDGES + 255) / 256, 256, 0, stream>>>(e_dst, E_EDGES, counts);
    scan_kernel<<<1, 1024, 0, stream>>>(counts, offsets, N_NODES);
    scatter_kernel<<<(E_EDGES + 255) / 256, 256, 0, stream>>>(e_src, e_dst, E_EDGES,
                                                              offsets, cursor, esrc);

    wt_layers<<<dim3(64, 4, LAYERS), 256, 0, stream>>>(Wq, Wk, Wv, Ws, Wt_hi, Wt_lo);
    wt_init<<<32, 256, 0, stream>>>(W_init, Wi_hi, Wi_lo);
    bias_cat<<<LAYERS * 4, 256, 0, stream>>>(bq, bk, bv, bs, bcat);
    conv_hi_lo<<<(N_NODES * 128 + 255) / 256, 256, 0, stream>>>(x, N_NODES * 128, x_hi, x_lo);

    const int rowTiles = M_PAD / 128;   // 157

    gemm_mfma<1><<<dim3(2, rowTiles), 256, 0, stream>>>(
        x_hi, x_lo, Wi_hi, Wi_lo, b_init, N_NODES, 128,
        nullptr, nullptr, h_hi, h_lo);

    for (int l = 0; l < LAYERS; ++l) {
        gemm_mfma<0><<<dim3(8, rowTiles), 256, 0, stream>>>(
            h_hi, h_lo,
            Wt_hi + (size_t)l * 1024 * 256, Wt_lo + (size_t)l * 1024 * 256,
            bcat + (size_t)l * 1024, N_NODES, 256,
            qs, kv, nullptr, nullptr);

        if (l < LAYERS - 1) {
            node_attn_kernel<0><<<(N_NODES + 3) / 4, 256, 0, stream>>>(
                qs, kv, offsets, esrc,
                Wbeta + (size_t)l * 768,
                ln_g + (size_t)l * 256, ln_b + (size_t)l * 256,
                nullptr, h_hi, h_lo);
        } else {
            node_attn_kernel<1><<<(N_NODES + 3) / 4, 256, 0, stream>>>(
                qs, kv, offsets, esrc,
                Wbeta + (size_t)l * 768,
                ln_g + (size_t)l * 256, ln_b + (size_t)l * 256,
                h, nullptr, nullptr);
        }
    }

    pool_kernel<<<(N_NODES + POOL_N - 1) / POOL_N, 256, 0, stream>>>(h, batch, N_NODES, sums, cnt);
    final_kernel<<<G_GRAPHS, 128, 0, stream>>>(sums, cnt, W_final, b_final, (float*)d_out);
}